// Round 1
// baseline (250.454 us; speedup 1.0000x reference)
//
#include <hip/hip_runtime.h>
#include <cstdint>
#include <cstddef>

// B=8, N=2048, C=512
// out = feature + softmax(Q K^T) @ V / sqrt(C),  Q = X Wq^T + bq etc.
// R11: gemm_qk / gemm_pv rewritten as 8-phase pipelined kernels (T3+T4
//      counted-vmcnt schedule, raw s_barrier, T5 setprio; T2 XOR swizzle
//      kept). prep / gemm_qkv unchanged from R10.
//
// Schedule invariants (derived by FIFO enumeration, see session notes):
//  - every vmcnt(N) guards the NEXT phase's ds_reads and sits before a
//    barrier, so cross-wave GLDS data is visible before it is read;
//  - every GLDS targets an LDS slot whose last ds_read completed at least
//    one barrier earlier (frags are register-held, so A0/B0 slots die
//    after ph1, B1 after ph2, A1 after ph3);
//  - vmcnt never drains to 0 in the steady loop.

typedef __bf16 bf16x8 __attribute__((ext_vector_type(8)));
typedef float f32x4 __attribute__((ext_vector_type(4)));
typedef short short4v __attribute__((ext_vector_type(4)));

__device__ __forceinline__ short f2b(float f) {
  union { float f; unsigned u; } u; u.f = f;
  unsigned r = (u.u + 0x7fffu + ((u.u >> 16) & 1u)) >> 16;  // RNE
  return (short)r;
}

#define GLDS(gptr, lptr) \
  __builtin_amdgcn_global_load_lds( \
      (const __attribute__((address_space(1))) unsigned int*)(const void*)(gptr), \
      (__attribute__((address_space(3))) unsigned int*)(void*)(lptr), 16, 0, 0)

// fragment load from a row-major [rows][64] LDS buffer with XOR-swizzled
// 8-short chunks. kq = chunk index before swizzle.
__device__ __forceinline__ bf16x8 ldfrag64(const short* buf, int row, int kq) {
  return *(const bf16x8*)(buf + row * 64 + ((kq ^ (row & 7)) * 8));
}

// -------- 8-phase helpers --------
template <int VM>
__device__ __forceinline__ void ph_mid() {
  if constexpr (VM >= 0) asm volatile("s_waitcnt vmcnt(%0)" ::"n"(VM) : "memory");
  __builtin_amdgcn_s_barrier();
  __builtin_amdgcn_s_setprio(1);
}
__device__ __forceinline__ void ph_end() {
  __builtin_amdgcn_s_setprio(0);
  __builtin_amdgcn_s_barrier();
  __builtin_amdgcn_sched_barrier(0);  // no ds_read may hoist above the barrier
}

__device__ __forceinline__ void ldA4(bf16x8 (&a)[4][2], const short* buf, int rb, int l4) {
#pragma unroll
  for (int j = 0; j < 4; ++j)
#pragma unroll
    for (int kk = 0; kk < 2; ++kk) a[j][kk] = ldfrag64(buf, rb + j * 16, kk * 4 + l4);
}
__device__ __forceinline__ void ld2(bf16x8 (&b)[2][2], const short* buf, int rb, int l4) {
#pragma unroll
  for (int n = 0; n < 2; ++n)
#pragma unroll
    for (int kk = 0; kk < 2; ++kk) b[n][kk] = ldfrag64(buf, rb + n * 16, kk * 4 + l4);
}
__device__ __forceinline__ void mm42(f32x4 (&acc)[8][4], const bf16x8 (&a)[4][2],
                                     const bf16x8 (&b)[2][2], int io, int no) {
#pragma unroll
  for (int j = 0; j < 4; ++j)
#pragma unroll
    for (int n = 0; n < 2; ++n)
#pragma unroll
      for (int kk = 0; kk < 2; ++kk)
        acc[io + j][no + n] = __builtin_amdgcn_mfma_f32_16x16x32_bf16(
            a[j][kk], b[n][kk], acc[io + j][no + n], 0, 0, 0);
}
__device__ __forceinline__ void mm22(f32x4 (&acc)[4][4], const bf16x8 (&a)[2][2],
                                     const bf16x8 (&b)[2][2], int io, int no) {
#pragma unroll
  for (int j = 0; j < 2; ++j)
#pragma unroll
    for (int n = 0; n < 2; ++n)
#pragma unroll
      for (int kk = 0; kk < 2; ++kk)
        acc[io + j][no + n] = __builtin_amdgcn_mfma_f32_16x16x32_bf16(
            a[j][kk], b[n][kk], acc[io + j][no + n], 0, 0, 0);
}

// ---------------- merged prep: feature->bf16, weights->bf16, bias pack, l=0 ----------------
__global__ __launch_bounds__(256) void prep(const float* __restrict__ f,
                                            const float* __restrict__ w0,
                                            const float* __restrict__ w1,
                                            const float* __restrict__ w2,
                                            const float* __restrict__ b0,
                                            const float* __restrict__ b1,
                                            const float* __restrict__ b2,
                                            short* __restrict__ Xb, short* __restrict__ Wb,
                                            float* __restrict__ biasP, float* __restrict__ l) {
  const int bid = blockIdx.x;
  const int t = threadIdx.x;
  if (bid < 8192) {                       // feature: 2097152 float4
    int i = bid * 256 + t;
    float4 v = ((const float4*)f)[i];
    short4v o = { f2b(v.x), f2b(v.y), f2b(v.z), f2b(v.w) };
    *(short4v*)(Xb + (size_t)i * 4) = o;
  } else if (bid < 8960) {                // weights: 196608 float4
    int i = (bid - 8192) * 256 + t;
    const float* src = (i < 65536) ? w0 : (i < 131072) ? w1 : w2;
    float4 v = ((const float4*)src)[i & 65535];
    short4v o = { f2b(v.x), f2b(v.y), f2b(v.z), f2b(v.w) };
    *(short4v*)(Wb + (size_t)i * 4) = o;
  } else {                                // 8 blocks: l zero (16384 f32) + bias (1536)
    int i = (bid - 8960) * 256 + t;       // 0..2047
    float4 z = { 0.f, 0.f, 0.f, 0.f };
    ((float4*)l)[i * 2] = z;
    ((float4*)l)[i * 2 + 1] = z;
    if (i < 1536) {
      const float* s = (i < 512) ? b0 : (i < 1024) ? b1 : b2;
      biasP[i] = s[i & 511];
    }
  }
}

// ---------------- fused QKV projection: 128x128 tile, BK=64 swizzled, 16x16x32 ----------------
__global__ __launch_bounds__(256) void gemm_qkv(const short* __restrict__ X,
                                                const short* __restrict__ Wall,
                                                const float* __restrict__ biasP,
                                                short* __restrict__ Out,
                                                short* __restrict__ VtOut) {
  __shared__ __align__(16) short Xs[128 * 64];
  __shared__ __align__(16) short Ws[128 * 64];
  const int z = blockIdx.z;
  const short* Wm = Wall + (size_t)z * 262144;
  const int m0 = blockIdx.y * 128, n0 = blockIdx.x * 128;
  const int t = threadIdx.x;
  const int lane = t & 63, w = t >> 6;
  const int wn = (w & 1) * 64, wm = (w >> 1) * 64;
  const int fr = lane & 15, l4 = lane >> 4;

  f32x4 acc[4][4] = {};

  for (int k0 = 0; k0 < 512; k0 += 64) {
    __syncthreads();
#pragma unroll
    for (int u = 0; u < 4; ++u) {
      int cc = t + u * 256;
      int r = cc >> 3, cs = cc & 7;
      int kk = ((cs ^ (r & 7)) * 8);
      GLDS(X + (size_t)(m0 + r) * 512 + k0 + kk, Xs + cc * 8);
      GLDS(Wm + (size_t)(n0 + r) * 512 + k0 + kk, Ws + cc * 8);
    }
    __syncthreads();
#pragma unroll
    for (int h = 0; h < 2; ++h) {
      bf16x8 wf[4], xf[4];
#pragma unroll
      for (int i = 0; i < 4; ++i) wf[i] = ldfrag64(Ws, wn + i * 16 + fr, h * 4 + l4);
#pragma unroll
      for (int j = 0; j < 4; ++j) xf[j] = ldfrag64(Xs, wm + j * 16 + fr, h * 4 + l4);
      if (z < 2) {
#pragma unroll
        for (int i = 0; i < 4; ++i)
#pragma unroll
          for (int j = 0; j < 4; ++j)
            acc[i][j] = __builtin_amdgcn_mfma_f32_16x16x32_bf16(wf[i], xf[j], acc[i][j], 0, 0, 0);
      } else {
#pragma unroll
        for (int i = 0; i < 4; ++i)
#pragma unroll
          for (int j = 0; j < 4; ++j)
            acc[i][j] = __builtin_amdgcn_mfma_f32_16x16x32_bf16(xf[i], wf[j], acc[i][j], 0, 0, 0);
      }
    }
  }

  const int rq = l4 * 4;
  if (z < 2) {
#pragma unroll
    for (int i = 0; i < 4; ++i) {
      int nb = n0 + wn + i * 16 + rq;
      float4 bs = *(const float4*)(biasP + z * 512 + nb);
#pragma unroll
      for (int j = 0; j < 4; ++j) {
        int m = m0 + wm + j * 16 + fr;
        short4v o = { f2b(acc[i][j][0] + bs.x), f2b(acc[i][j][1] + bs.y),
                      f2b(acc[i][j][2] + bs.z), f2b(acc[i][j][3] + bs.w) };
        *(short4v*)(Out + (size_t)z * 8388608 + (size_t)m * 512 + nb) = o;
      }
    }
  } else {
    const int zB = blockIdx.y >> 4;
    const int mb = m0 & 2047;
#pragma unroll
    for (int j = 0; j < 4; ++j) {
      int d = n0 + wn + j * 16 + fr;
      float bd = biasP[1024 + d];
#pragma unroll
      for (int i = 0; i < 4; ++i) {
        int mloc = mb + wm + i * 16 + rq;
        short4v o = { f2b(acc[i][j][0] + bd), f2b(acc[i][j][1] + bd),
                      f2b(acc[i][j][2] + bd), f2b(acc[i][j][3] + bd) };
        *(short4v*)(VtOut + (size_t)zB * 1048576 + (size_t)d * 2048 + mloc) = o;
      }
    }
  }
}

// ---------------- QK^T: 256x256 tile, 8-phase pipelined, exp epilogue ----------------
// A = K rows (keys, C quad-rows), B = Q rows (queries, C cols).
// 8 waves as 2(A)x4(B); per-wave 128x64 output via half-strided fragments:
//   A-frag i: row = aw + (i&3)*16 + (i>>2)*128   (aw = (w>>2)*64)
//   B-frag n: row = bw + (n&1)*16 + (n>>1)*128   (bw = (w&3)*32)
// Phases per K-tile: (0,0) (0,1) (1,1) (1,0); b0/b1/af register-held.
// Prefetch slots: ph1->(kt+1).A1, ph2->(kt+2).A0, ph3->(kt+2).B0, ph4->(kt+2).B1.
// Steady waits: vmcnt(10) at ph1/ph2/ph4 (5 half-tiles in flight).
__global__ __launch_bounds__(512, 2) void gemm_qk8(const short* __restrict__ Q,
                                                   const short* __restrict__ Kb,
                                                   short* __restrict__ P,
                                                   float* __restrict__ l) {
  __shared__ __align__(16) short As[2][16384];  // keys   256x64 per buffer
  __shared__ __align__(16) short Bs[2][16384];  // queries
  const int z = blockIdx.z;
  const short* __restrict__ A = Kb + (size_t)z * 1048576;
  const short* __restrict__ B = Q + (size_t)z * 1048576;
  const int m0 = blockIdx.y * 256;  // keys
  const int n0 = blockIdx.x * 256;  // queries
  const int t = threadIdx.x;
  const int lane = t & 63, w = t >> 6;
  const int aw = (w >> 2) * 64, bw = (w & 3) * 32;
  const int fr = lane & 15, l4 = lane >> 4;
  const int r0 = t >> 3;
  const int kswz = ((t & 7) ^ (r0 & 7)) * 8;  // pre-swizzled global source chunk
  const short* pA = A + (size_t)(m0 + r0) * 512 + kswz;
  const short* pB = B + (size_t)(n0 + r0) * 512 + kswz;

#define QK_STG_A(buf, h, kt) do { \
    GLDS(pA + (size_t)((h) * 128) * 512 + (kt) * 64, &As[(buf)][(h) * 8192 + t * 8]); \
    GLDS(pA + (size_t)((h) * 128 + 64) * 512 + (kt) * 64, &As[(buf)][(h) * 8192 + 4096 + t * 8]); \
  } while (0)
#define QK_STG_B(buf, h, kt) do { \
    GLDS(pB + (size_t)((h) * 128) * 512 + (kt) * 64, &Bs[(buf)][(h) * 8192 + t * 8]); \
    GLDS(pB + (size_t)((h) * 128 + 64) * 512 + (kt) * 64, &Bs[(buf)][(h) * 8192 + 4096 + t * 8]); \
  } while (0)

  f32x4 acc[8][4] = {};

  // prologue: T0.{A0,B0,B1,A1}, T1.{A0,B0,B1}  (14 loads); keep newest 5 halves.
  QK_STG_A(0, 0, 0); QK_STG_B(0, 0, 0); QK_STG_B(0, 1, 0); QK_STG_A(0, 1, 0);
  QK_STG_A(1, 0, 1); QK_STG_B(1, 0, 1); QK_STG_B(1, 1, 1);
  asm volatile("s_waitcnt vmcnt(10)" ::: "memory");
  __builtin_amdgcn_s_barrier();
  __builtin_amdgcn_sched_barrier(0);

  bf16x8 af[4][2], b0[2][2], b1[2][2];
  for (int kt = 0; kt < 6; ++kt) {
    const int c = kt & 1;
    const short* Ac = &As[c][0];
    const short* Bc = &Bs[c][0];
    // ph1 (A0,B0)
    ldA4(af, Ac, aw + fr, l4); ld2(b0, Bc, bw + fr, l4);
    QK_STG_A(c ^ 1, 1, kt + 1);
    ph_mid<10>(); mm42(acc, af, b0, 0, 0); ph_end();
    // ph2 (A0,B1)
    ld2(b1, Bc, 128 + bw + fr, l4);
    QK_STG_A(c, 0, kt + 2);
    ph_mid<10>(); mm42(acc, af, b1, 0, 2); ph_end();
    // ph3 (A1,B1)
    ldA4(af, Ac, 128 + aw + fr, l4);
    QK_STG_B(c, 0, kt + 2);
    ph_mid<-1>(); mm42(acc, af, b1, 4, 2); ph_end();
    // ph4 (A1,B0) - all frags register-held
    QK_STG_B(c, 1, kt + 2);
    ph_mid<10>(); mm42(acc, af, b0, 4, 0); ph_end();
  }
  {  // kt = 6 (buf 0): only T7.A1 left to stage; drain 10 -> 8 -> 4
    const short *Ac = &As[0][0], *Bc = &Bs[0][0];
    ldA4(af, Ac, aw + fr, l4); ld2(b0, Bc, bw + fr, l4);
    QK_STG_A(1, 1, 7);
    ph_mid<10>(); mm42(acc, af, b0, 0, 0); ph_end();
    ld2(b1, Bc, 128 + bw + fr, l4);
    ph_mid<8>();  mm42(acc, af, b1, 0, 2); ph_end();
    ldA4(af, Ac, 128 + aw + fr, l4);
    ph_mid<-1>(); mm42(acc, af, b1, 4, 2); ph_end();
    ph_mid<4>();  mm42(acc, af, b0, 4, 0); ph_end();
  }
  {  // kt = 7 (buf 1): drain 2 -> 0
    const short *Ac = &As[1][0], *Bc = &Bs[1][0];
    ldA4(af, Ac, aw + fr, l4); ld2(b0, Bc, bw + fr, l4);
    ph_mid<2>();  mm42(acc, af, b0, 0, 0); ph_end();
    ld2(b1, Bc, 128 + bw + fr, l4);
    ph_mid<0>();  mm42(acc, af, b1, 0, 2); ph_end();
    ldA4(af, Ac, 128 + aw + fr, l4);
    ph_mid<-1>(); mm42(acc, af, b1, 4, 2); ph_end();
    ph_mid<-1>(); mm42(acc, af, b0, 4, 0); ph_end();
  }
#undef QK_STG_A
#undef QK_STG_B

  // epilogue: e = exp(score), store bf16 P[query][key], row-sum atomics.
  const float LOG2E = 1.4426950408889634f;
  float rs[4] = { 0.f, 0.f, 0.f, 0.f };
#pragma unroll
  for (int i = 0; i < 8; ++i) {
    const int key = m0 + aw + (i & 3) * 16 + (i >> 2) * 128 + l4 * 4;
#pragma unroll
    for (int n = 0; n < 4; ++n) {
      const int q = n0 + bw + (n & 1) * 16 + (n >> 1) * 128 + fr;
      short4v o;
      float part = 0.f;
#pragma unroll
      for (int r = 0; r < 4; ++r) {
        float e = exp2f(acc[i][n][r] * LOG2E);
        o[r] = f2b(e);
        part += e;
      }
      *(short4v*)(P + (size_t)z * 4194304 + (size_t)q * 2048 + key) = o;
      rs[n] += part;
    }
  }
#pragma unroll
  for (int n = 0; n < 4; ++n) {
    rs[n] += __shfl_xor(rs[n], 16);
    rs[n] += __shfl_xor(rs[n], 32);
  }
  if (l4 == 0) {
#pragma unroll
    for (int n = 0; n < 4; ++n)
      atomicAdd(&l[z * 2048 + n0 + bw + (n & 1) * 16 + (n >> 1) * 128 + fr], rs[n]);
  }
}

// ---------------- PV: 128(d) x 256(q) tile, 8-phase pipelined, K=2048 ----------------
// A = Vt rows (d, C quad-rows), B = P rows (queries, C cols).
// 8 waves 2(A)x4(B); per-wave 64x64 via half-strided fragments:
//   A-frag i: row = aw + (i&1)*16 + (i>>1)*64    (aw = (w>>2)*32)
//   B-frag n: row = bw + (n&1)*16 + (n>>1)*128   (bw = (w&3)*32)
// A-half = 1 load/wave, B-half = 2 loads/wave -> steady waits vmcnt(7)/7/-/8.
__global__ __launch_bounds__(512, 2) void gemm_pv8(const short* __restrict__ Pm,
                                                   const short* __restrict__ Vt,
                                                   const float* __restrict__ l,
                                                   const float* __restrict__ resid,
                                                   float* __restrict__ out, float scale) {
  __shared__ __align__(16) short As[2][8192];   // Vt rows: 128x64
  __shared__ __align__(16) short Bs[2][16384];  // P rows: 256x64
  const int z = blockIdx.z;
  const short* __restrict__ A = Vt + (size_t)z * 1048576;  // [512][2048]
  const short* __restrict__ B = Pm + (size_t)z * 4194304;  // [2048][2048]
  const int d0 = blockIdx.x * 128;
  const int n0 = blockIdx.y * 256;
  const int t = threadIdx.x;
  const int lane = t & 63, w = t >> 6;
  const int aw = (w >> 2) * 32, bw = (w & 3) * 32;
  const int fr = lane & 15, l4 = lane >> 4;
  const int r0 = t >> 3;
  const int kswz = ((t & 7) ^ (r0 & 7)) * 8;
  const short* pA = A + (size_t)(d0 + r0) * 2048 + kswz;
  const short* pB = B + (size_t)(n0 + r0) * 2048 + kswz;

#define PV_STG_A(buf, h, kt) \
    GLDS(pA + (size_t)((h) * 64) * 2048 + (kt) * 64, &As[(buf)][(h) * 4096 + t * 8])
#define PV_STG_B(buf, h, kt) do { \
    GLDS(pB + (size_t)((h) * 128) * 2048 + (kt) * 64, &Bs[(buf)][(h) * 8192 + t * 8]); \
    GLDS(pB + (size_t)((h) * 128 + 64) * 2048 + (kt) * 64, &Bs[(buf)][(h) * 8192 + 4096 + t * 8]); \
  } while (0)

  f32x4 acc[4][4] = {};

  // prologue: T0.{A0,B0,B1,A1}, T1.{A0,B0,B1}  (11 loads); keep newest 8 loads.
  PV_STG_A(0, 0, 0); PV_STG_B(0, 0, 0); PV_STG_B(0, 1, 0); PV_STG_A(0, 1, 0);
  PV_STG_A(1, 0, 1); PV_STG_B(1, 0, 1); PV_STG_B(1, 1, 1);
  asm volatile("s_waitcnt vmcnt(8)" ::: "memory");
  __builtin_amdgcn_s_barrier();
  __builtin_amdgcn_sched_barrier(0);

  bf16x8 a[2][2], b0[2][2], b1[2][2];
  for (int kt = 0; kt < 30; ++kt) {
    const int c = kt & 1;
    const short* Ac = &As[c][0];
    const short* Bc = &Bs[c][0];
    // ph1 (A0,B0)
    ld2(a, Ac, aw + fr, l4); ld2(b0, Bc, bw + fr, l4);
    PV_STG_A(c ^ 1, 1, kt + 1);
    ph_mid<7>(); mm22(acc, a, b0, 0, 0); ph_end();
    // ph2 (A0,B1)
    ld2(b1, Bc, 128 + bw + fr, l4);
    PV_STG_A(c, 0, kt + 2);
    ph_mid<7>(); mm22(acc, a, b1, 0, 2); ph_end();
    // ph3 (A1,B1)
    ld2(a, Ac, 64 + aw + fr, l4);
    PV_STG_B(c, 0, kt + 2);
    ph_mid<-1>(); mm22(acc, a, b1, 2, 2); ph_end();
    // ph4 (A1,B0)
    PV_STG_B(c, 1, kt + 2);
    ph_mid<8>(); mm22(acc, a, b0, 2, 0); ph_end();
  }
  {  // kt = 30 (buf 0): only T31.A1 left; drain 7 -> 6 -> 3
    const short *Ac = &As[0][0], *Bc = &Bs[0][0];
    ld2(a, Ac, aw + fr, l4); ld2(b0, Bc, bw + fr, l4);
    PV_STG_A(1, 1, 31);
    ph_mid<7>(); mm22(acc, a, b0, 0, 0); ph_end();
    ld2(b1, Bc, 128 + bw + fr, l4);
    ph_mid<6>(); mm22(acc, a, b1, 0, 2); ph_end();
    ld2(a, Ac, 64 + aw + fr, l4);
    ph_mid<-1>(); mm22(acc, a, b1, 2, 2); ph_end();
    ph_mid<3>(); mm22(acc, a, b0, 2, 0); ph_end();
  }
  {  // kt = 31 (buf 1): drain 1 -> 0
    const short *Ac = &As[1][0], *Bc = &Bs[1][0];
    ld2(a, Ac, aw + fr, l4); ld2(b0, Bc, bw + fr, l4);
    ph_mid<1>(); mm22(acc, a, b0, 0, 0); ph_end();
    ld2(b1, Bc, 128 + bw + fr, l4);
    ph_mid<0>(); mm22(acc, a, b1, 0, 2); ph_end();
    ld2(a, Ac, 64 + aw + fr, l4);
    ph_mid<-1>(); mm22(acc, a, b1, 2, 2); ph_end();
    ph_mid<-1>(); mm22(acc, a, b0, 2, 0); ph_end();
  }
#undef PV_STG_A
#undef PV_STG_B

  // epilogue: out = resid + acc * (scale / l[q])
  float linv[4];
#pragma unroll
  for (int n = 0; n < 4; ++n) {
    const int q = n0 + bw + (n & 1) * 16 + (n >> 1) * 128 + fr;
    linv[n] = scale / l[z * 2048 + q];
  }
#pragma unroll
  for (int n = 0; n < 4; ++n) {
    const int q = n0 + bw + (n & 1) * 16 + (n >> 1) * 128 + fr;
#pragma unroll
    for (int i = 0; i < 4; ++i) {
      const int d = d0 + aw + (i & 1) * 16 + (i >> 1) * 64 + l4 * 4;
      const size_t idx = (size_t)z * 1048576 + (size_t)q * 512 + d;
      float4 rv = *(const float4*)(resid + idx);
      float4 o = { rv.x + acc[i][n][0] * linv[n], rv.y + acc[i][n][1] * linv[n],
                   rv.z + acc[i][n][2] * linv[n], rv.w + acc[i][n][3] * linv[n] };
      *(float4*)(out + idx) = o;
    }
  }
}

extern "C" void kernel_launch(void* const* d_in, const int* in_sizes, int n_in,
                              void* d_out, int out_size, void* d_ws, size_t ws_size,
                              hipStream_t stream) {
  const float* feature = (const float*)d_in[0];
  const float* wq = (const float*)d_in[1];
  const float* bq = (const float*)d_in[2];
  const float* wk = (const float*)d_in[3];
  const float* bk = (const float*)d_in[4];
  const float* wv = (const float*)d_in[5];
  const float* bv = (const float*)d_in[6];
  float* out = (float*)d_out;

  const size_t MN = (size_t)16384 * 512;
  short* Xb = (short*)d_ws;       // MN
  short* Wb = Xb + MN;            // 3 * 262144
  short* Q = Wb + 786432;         // MN (K follows contiguously)
  short* K = Q + MN;
  short* Vt = K + MN;             // [8][512][2048]
  short* P = Vt + MN;             // [8][2048][2048] unnormalized exp
  float* biasP = (float*)(P + (size_t)8 * 2048 * 2048);  // [3][512]
  float* l = biasP + 1536;        // [8*2048] row sums of exp

  prep<<<8968, 256, 0, stream>>>(feature, wq, wk, wv, bq, bk, bv, Xb, Wb, biasP, l);

  gemm_qkv<<<dim3(4, 128, 3), 256, 0, stream>>>(Xb, Wb, biasP, Q, Vt);
  gemm_qk8<<<dim3(8, 8, 8), 512, 0, stream>>>(Q, K, P, l);

  const float iscl = 0.044194173824159216f;  // 1/sqrt(512)
  gemm_pv8<<<dim3(4, 8, 8), 512, 0, stream>>>(P, Vt, l, feature, out, iscl);
}

// Round 2
// 229.930 us; speedup vs baseline: 1.0893x; 1.0893x over previous
//
#include <hip/hip_runtime.h>
#include <cstdint>
#include <cstddef>

// B=8, N=2048, C=512
// out = feature + softmax(Q K^T) @ V / sqrt(C),  Q = X Wq^T + bq etc.
// R12: qk8/pv8 pipeline made compiler-proof:
//  - fragment loads are inline-asm ds_read_b128 (SIInsertWaitcnts treats
//    plain ds_reads after global_load_lds as aliasing the LDS-DMA and
//    inserts vmcnt(0) drains every phase -> R11 was a no-op);
//  - explicit s_waitcnt lgkmcnt(0) + sched_barrier(0) after each mid
//    barrier (rule #18);
//  - ONE counted vmcnt per K-tile (qk8: vmcnt(6), pv8: vmcnt(5)), FIFO
//    re-enumerated incl. tails; all LDS slot WAR windows >= 1 barrier.
//  - kk-outer MFMA order (same per-acc summation order, 8-instr dep gap);
//  - XCD remap: one batch z per XCD (qk8: Q+K = 4MB = one L2).
// prep / gemm_qkv unchanged from R10.

typedef __bf16 bf16x8 __attribute__((ext_vector_type(8)));
typedef float f32x4 __attribute__((ext_vector_type(4)));
typedef short short4v __attribute__((ext_vector_type(4)));

__device__ __forceinline__ short f2b(float f) {
  union { float f; unsigned u; } u; u.f = f;
  unsigned r = (u.u + 0x7fffu + ((u.u >> 16) & 1u)) >> 16;  // RNE
  return (short)r;
}

#define GLDS(gptr, lptr) \
  __builtin_amdgcn_global_load_lds( \
      (const __attribute__((address_space(1))) unsigned int*)(const void*)(gptr), \
      (__attribute__((address_space(3))) unsigned int*)(void*)(lptr), 16, 0, 0)

// plain fragment load (compiler-managed waits) - used by gemm_qkv only.
__device__ __forceinline__ bf16x8 ldfrag64(const short* buf, int row, int kq) {
  return *(const bf16x8*)(buf + row * 64 + ((kq ^ (row & 7)) * 8));
}

// asm fragment load: invisible to SIInsertWaitcnts -> no auto vmcnt drain.
// Completion is ONLY guaranteed by the explicit lgkmcnt(0) below.
__device__ __forceinline__ bf16x8 ldfrag_a(const short* buf, int row, int kq) {
  const short* p = buf + row * 64 + ((kq ^ (row & 7)) * 8);
  bf16x8 r;
  asm volatile("ds_read_b128 %0, %1"
               : "=v"(r)
               : "v"((const __attribute__((address_space(3))) short*)(const void*)p));
  return r;
}

#define LGKM0_SB() do { \
    asm volatile("s_waitcnt lgkmcnt(0)" ::: "memory"); \
    __builtin_amdgcn_sched_barrier(0); } while (0)
#define VMW(n) asm volatile("s_waitcnt vmcnt(" #n ")" ::: "memory")
#define SBAR() __builtin_amdgcn_s_barrier()
#define PRIO1() __builtin_amdgcn_s_setprio(1)
#define PRIO0() __builtin_amdgcn_s_setprio(0)

__device__ __forceinline__ void ldA4(bf16x8 (&a)[4][2], const short* buf, int rb, int l4) {
#pragma unroll
  for (int j = 0; j < 4; ++j)
#pragma unroll
    for (int kk = 0; kk < 2; ++kk) a[j][kk] = ldfrag_a(buf, rb + j * 16, kk * 4 + l4);
}
__device__ __forceinline__ void ld2(bf16x8 (&b)[2][2], const short* buf, int rb, int l4) {
#pragma unroll
  for (int n = 0; n < 2; ++n)
#pragma unroll
    for (int kk = 0; kk < 2; ++kk) b[n][kk] = ldfrag_a(buf, rb + n * 16, kk * 4 + l4);
}
// kk-outer: dependent same-acc MFMAs are 8 apart; per-acc k-order unchanged.
__device__ __forceinline__ void mm42(f32x4 (&acc)[8][4], const bf16x8 (&a)[4][2],
                                     const bf16x8 (&b)[2][2], int io, int no) {
#pragma unroll
  for (int kk = 0; kk < 2; ++kk)
#pragma unroll
    for (int j = 0; j < 4; ++j)
#pragma unroll
      for (int n = 0; n < 2; ++n)
        acc[io + j][no + n] = __builtin_amdgcn_mfma_f32_16x16x32_bf16(
            a[j][kk], b[n][kk], acc[io + j][no + n], 0, 0, 0);
}
__device__ __forceinline__ void mm22(f32x4 (&acc)[4][4], const bf16x8 (&a)[2][2],
                                     const bf16x8 (&b)[2][2], int io, int no) {
#pragma unroll
  for (int kk = 0; kk < 2; ++kk)
#pragma unroll
    for (int j = 0; j < 2; ++j)
#pragma unroll
      for (int n = 0; n < 2; ++n)
        acc[io + j][no + n] = __builtin_amdgcn_mfma_f32_16x16x32_bf16(
            a[j][kk], b[n][kk], acc[io + j][no + n], 0, 0, 0);
}

// ---------------- merged prep: feature->bf16, weights->bf16, bias pack, l=0 ----------------
__global__ __launch_bounds__(256) void prep(const float* __restrict__ f,
                                            const float* __restrict__ w0,
                                            const float* __restrict__ w1,
                                            const float* __restrict__ w2,
                                            const float* __restrict__ b0,
                                            const float* __restrict__ b1,
                                            const float* __restrict__ b2,
                                            short* __restrict__ Xb, short* __restrict__ Wb,
                                            float* __restrict__ biasP, float* __restrict__ l) {
  const int bid = blockIdx.x;
  const int t = threadIdx.x;
  if (bid < 8192) {                       // feature: 2097152 float4
    int i = bid * 256 + t;
    float4 v = ((const float4*)f)[i];
    short4v o = { f2b(v.x), f2b(v.y), f2b(v.z), f2b(v.w) };
    *(short4v*)(Xb + (size_t)i * 4) = o;
  } else if (bid < 8960) {                // weights: 196608 float4
    int i = (bid - 8192) * 256 + t;
    const float* src = (i < 65536) ? w0 : (i < 131072) ? w1 : w2;
    float4 v = ((const float4*)src)[i & 65535];
    short4v o = { f2b(v.x), f2b(v.y), f2b(v.z), f2b(v.w) };
    *(short4v*)(Wb + (size_t)i * 4) = o;
  } else {                                // 8 blocks: l zero (16384 f32) + bias (1536)
    int i = (bid - 8960) * 256 + t;       // 0..2047
    float4 z = { 0.f, 0.f, 0.f, 0.f };
    ((float4*)l)[i * 2] = z;
    ((float4*)l)[i * 2 + 1] = z;
    if (i < 1536) {
      const float* s = (i < 512) ? b0 : (i < 1024) ? b1 : b2;
      biasP[i] = s[i & 511];
    }
  }
}

// ---------------- fused QKV projection: 128x128 tile, BK=64 swizzled, 16x16x32 ----------------
__global__ __launch_bounds__(256) void gemm_qkv(const short* __restrict__ X,
                                                const short* __restrict__ Wall,
                                                const float* __restrict__ biasP,
                                                short* __restrict__ Out,
                                                short* __restrict__ VtOut) {
  __shared__ __align__(16) short Xs[128 * 64];
  __shared__ __align__(16) short Ws[128 * 64];
  const int z = blockIdx.z;
  const short* Wm = Wall + (size_t)z * 262144;
  const int m0 = blockIdx.y * 128, n0 = blockIdx.x * 128;
  const int t = threadIdx.x;
  const int lane = t & 63, w = t >> 6;
  const int wn = (w & 1) * 64, wm = (w >> 1) * 64;
  const int fr = lane & 15, l4 = lane >> 4;

  f32x4 acc[4][4] = {};

  for (int k0 = 0; k0 < 512; k0 += 64) {
    __syncthreads();
#pragma unroll
    for (int u = 0; u < 4; ++u) {
      int cc = t + u * 256;
      int r = cc >> 3, cs = cc & 7;
      int kk = ((cs ^ (r & 7)) * 8);
      GLDS(X + (size_t)(m0 + r) * 512 + k0 + kk, Xs + cc * 8);
      GLDS(Wm + (size_t)(n0 + r) * 512 + k0 + kk, Ws + cc * 8);
    }
    __syncthreads();
#pragma unroll
    for (int h = 0; h < 2; ++h) {
      bf16x8 wf[4], xf[4];
#pragma unroll
      for (int i = 0; i < 4; ++i) wf[i] = ldfrag64(Ws, wn + i * 16 + fr, h * 4 + l4);
#pragma unroll
      for (int j = 0; j < 4; ++j) xf[j] = ldfrag64(Xs, wm + j * 16 + fr, h * 4 + l4);
      if (z < 2) {
#pragma unroll
        for (int i = 0; i < 4; ++i)
#pragma unroll
          for (int j = 0; j < 4; ++j)
            acc[i][j] = __builtin_amdgcn_mfma_f32_16x16x32_bf16(wf[i], xf[j], acc[i][j], 0, 0, 0);
      } else {
#pragma unroll
        for (int i = 0; i < 4; ++i)
#pragma unroll
          for (int j = 0; j < 4; ++j)
            acc[i][j] = __builtin_amdgcn_mfma_f32_16x16x32_bf16(xf[i], wf[j], acc[i][j], 0, 0, 0);
      }
    }
  }

  const int rq = l4 * 4;
  if (z < 2) {
#pragma unroll
    for (int i = 0; i < 4; ++i) {
      int nb = n0 + wn + i * 16 + rq;
      float4 bs = *(const float4*)(biasP + z * 512 + nb);
#pragma unroll
      for (int j = 0; j < 4; ++j) {
        int m = m0 + wm + j * 16 + fr;
        short4v o = { f2b(acc[i][j][0] + bs.x), f2b(acc[i][j][1] + bs.y),
                      f2b(acc[i][j][2] + bs.z), f2b(acc[i][j][3] + bs.w) };
        *(short4v*)(Out + (size_t)z * 8388608 + (size_t)m * 512 + nb) = o;
      }
    }
  } else {
    const int zB = blockIdx.y >> 4;
    const int mb = m0 & 2047;
#pragma unroll
    for (int j = 0; j < 4; ++j) {
      int d = n0 + wn + j * 16 + fr;
      float bd = biasP[1024 + d];
#pragma unroll
      for (int i = 0; i < 4; ++i) {
        int mloc = mb + wm + i * 16 + rq;
        short4v o = { f2b(acc[i][j][0] + bd), f2b(acc[i][j][1] + bd),
                      f2b(acc[i][j][2] + bd), f2b(acc[i][j][3] + bd) };
        *(short4v*)(VtOut + (size_t)zB * 1048576 + (size_t)d * 2048 + mloc) = o;
      }
    }
  }
}

// ---------------- QK^T: 256x256 tile, 4-phase/K-tile pipelined, exp epilogue ----------------
// A = K rows (keys), B = Q rows (queries). 8 waves 2(A)x4(B), per-wave 128x64.
// Issue slots: ph1->T(kt+1).A1, ph2->T(kt+2).A0, ph3->T(kt+2).B0, ph4->T(kt+2).B1.
// Single wait per K-tile: vmcnt(6) at ph4 guarantees ALL of T(kt+1).
// WAR: every slot overwrite is >=1 barrier after its readers' lgkmcnt(0).
__global__ __launch_bounds__(512, 2) void gemm_qk8(const short* __restrict__ Q,
                                                   const short* __restrict__ Kb,
                                                   short* __restrict__ P,
                                                   float* __restrict__ l) {
  __shared__ __align__(16) short As[2][16384];  // keys   256x64 per buffer
  __shared__ __align__(16) short Bs[2][16384];  // queries
  // XCD remap: dispatch id -> one batch z per XCD (Q_z+K_z = 4MB = one L2).
  const int id = blockIdx.x + blockIdx.y * 8 + blockIdx.z * 64;
  const int swz = (id & 7) * 64 + (id >> 3);
  const int z = swz >> 6;
  const int m0 = ((swz >> 3) & 7) * 256;  // keys
  const int n0 = (swz & 7) * 256;         // queries
  const short* __restrict__ A = Kb + (size_t)z * 1048576;
  const short* __restrict__ B = Q + (size_t)z * 1048576;
  const int t = threadIdx.x;
  const int lane = t & 63, w = t >> 6;
  const int aw = (w >> 2) * 64, bw = (w & 3) * 32;
  const int fr = lane & 15, l4 = lane >> 4;
  const int r0 = t >> 3;
  const int kswz = ((t & 7) ^ (r0 & 7)) * 8;  // pre-swizzled global source chunk
  const short* pA = A + (size_t)(m0 + r0) * 512 + kswz;
  const short* pB = B + (size_t)(n0 + r0) * 512 + kswz;

#define QK_STG_A(buf, h, kt) do { \
    GLDS(pA + (size_t)((h) * 128) * 512 + (kt) * 64, &As[(buf)][(h) * 8192 + t * 8]); \
    GLDS(pA + (size_t)((h) * 128 + 64) * 512 + (kt) * 64, &As[(buf)][(h) * 8192 + 4096 + t * 8]); \
  } while (0)
#define QK_STG_B(buf, h, kt) do { \
    GLDS(pB + (size_t)((h) * 128) * 512 + (kt) * 64, &Bs[(buf)][(h) * 8192 + t * 8]); \
    GLDS(pB + (size_t)((h) * 128 + 64) * 512 + (kt) * 64, &Bs[(buf)][(h) * 8192 + 4096 + t * 8]); \
  } while (0)

  f32x4 acc[8][4] = {};

  // prologue: T0.{A0,B0,B1,A1}, T1.{A0,B0,B1} = 14 loads; wait ALL of T0.
  QK_STG_A(0, 0, 0); QK_STG_B(0, 0, 0); QK_STG_B(0, 1, 0); QK_STG_A(0, 1, 0);
  QK_STG_A(1, 0, 1); QK_STG_B(1, 0, 1); QK_STG_B(1, 1, 1);
  VMW(6);
  SBAR();

  bf16x8 af[4][2], b0[2][2], b1[2][2];
  for (int kt = 0; kt < 6; ++kt) {
    const int c = kt & 1;
    const short* Ac = &As[c][0];
    const short* Bc = &Bs[c][0];
    // ph1 (A0,B0)
    ldA4(af, Ac, aw + fr, l4); ld2(b0, Bc, bw + fr, l4);
    QK_STG_A(c ^ 1, 1, kt + 1);
    SBAR(); LGKM0_SB(); PRIO1(); mm42(acc, af, b0, 0, 0); PRIO0(); SBAR();
    // ph2 (A0,B1)
    ld2(b1, Bc, 128 + bw + fr, l4);
    QK_STG_A(c, 0, kt + 2);
    SBAR(); LGKM0_SB(); PRIO1(); mm42(acc, af, b1, 0, 2); PRIO0(); SBAR();
    // ph3 (A1,B1)
    ldA4(af, Ac, 128 + aw + fr, l4);
    QK_STG_B(c, 0, kt + 2);
    SBAR(); LGKM0_SB(); PRIO1(); mm42(acc, af, b1, 4, 2); PRIO0(); SBAR();
    // ph4 (A1,B0) - frags register-held; wait ALL of T(kt+1).
    QK_STG_B(c, 1, kt + 2);
    VMW(6);
    SBAR(); PRIO1(); mm42(acc, af, b0, 4, 0); PRIO0(); SBAR();
  }
  {  // kt = 6 (buf 0): only T7.A1 left; ph4 waits ALL of T7 -> vmcnt(0).
    const short *Ac = &As[0][0], *Bc = &Bs[0][0];
    ldA4(af, Ac, aw + fr, l4); ld2(b0, Bc, bw + fr, l4);
    QK_STG_A(1, 1, 7);
    SBAR(); LGKM0_SB(); PRIO1(); mm42(acc, af, b0, 0, 0); PRIO0(); SBAR();
    ld2(b1, Bc, 128 + bw + fr, l4);
    SBAR(); LGKM0_SB(); PRIO1(); mm42(acc, af, b1, 0, 2); PRIO0(); SBAR();
    ldA4(af, Ac, 128 + aw + fr, l4);
    SBAR(); LGKM0_SB(); PRIO1(); mm42(acc, af, b1, 4, 2); PRIO0(); SBAR();
    VMW(0);
    SBAR(); PRIO1(); mm42(acc, af, b0, 4, 0); PRIO0(); SBAR();
  }
  {  // kt = 7 (buf 1): no staging, no vmem waits.
    const short *Ac = &As[1][0], *Bc = &Bs[1][0];
    ldA4(af, Ac, aw + fr, l4); ld2(b0, Bc, bw + fr, l4);
    SBAR(); LGKM0_SB(); PRIO1(); mm42(acc, af, b0, 0, 0); PRIO0(); SBAR();
    ld2(b1, Bc, 128 + bw + fr, l4);
    SBAR(); LGKM0_SB(); PRIO1(); mm42(acc, af, b1, 0, 2); PRIO0(); SBAR();
    ldA4(af, Ac, 128 + aw + fr, l4);
    SBAR(); LGKM0_SB(); PRIO1(); mm42(acc, af, b1, 4, 2); PRIO0();
    mm42(acc, af, b0, 4, 0);
  }
#undef QK_STG_A
#undef QK_STG_B

  // epilogue: e = exp(score), store bf16 P[query][key], row-sum atomics.
  const float LOG2E = 1.4426950408889634f;
  float rs[4] = { 0.f, 0.f, 0.f, 0.f };
#pragma unroll
  for (int i = 0; i < 8; ++i) {
    const int key = m0 + aw + (i & 3) * 16 + (i >> 2) * 128 + l4 * 4;
#pragma unroll
    for (int n = 0; n < 4; ++n) {
      const int q = n0 + bw + (n & 1) * 16 + (n >> 1) * 128 + fr;
      short4v o;
      float part = 0.f;
#pragma unroll
      for (int r = 0; r < 4; ++r) {
        float e = exp2f(acc[i][n][r] * LOG2E);
        o[r] = f2b(e);
        part += e;
      }
      *(short4v*)(P + (size_t)z * 4194304 + (size_t)q * 2048 + key) = o;
      rs[n] += part;
    }
  }
#pragma unroll
  for (int n = 0; n < 4; ++n) {
    rs[n] += __shfl_xor(rs[n], 16);
    rs[n] += __shfl_xor(rs[n], 32);
  }
  if (l4 == 0) {
#pragma unroll
    for (int n = 0; n < 4; ++n)
      atomicAdd(&l[z * 2048 + n0 + bw + (n & 1) * 16 + (n >> 1) * 128 + fr], rs[n]);
  }
}

// ---------------- PV: 128(d) x 256(q) tile, 2-phase/K-tile pipelined, K=2048 ----------------
// A = Vt rows (d), B = P rows (queries). 8 waves 2(A)x4(B), per-wave 64x64.
// pha: MFMA(A0,b0)+(A0,b1); issues T(kt+1).A1.
// phb: MFMA(A1,b1)+(A1,b0); issues T(kt+2).{A0,B0,B1}; waits vmcnt(5) = ALL T(kt+1).
// WAR: A0 slot read in pha, overwritten by GLDS issued in phb (>=1 barrier);
//      B0/B1 read in pha, overwritten in phb; A1 read in phb, overwritten at
//      (kt+1).pha (>=2 barriers).
__global__ __launch_bounds__(512, 2) void gemm_pv8(const short* __restrict__ Pm,
                                                   const short* __restrict__ Vt,
                                                   const float* __restrict__ l,
                                                   const float* __restrict__ resid,
                                                   float* __restrict__ out, float scale) {
  __shared__ __align__(16) short As[2][8192];   // Vt rows: 128x64
  __shared__ __align__(16) short Bs[2][16384];  // P rows: 256x64
  // XCD remap: one batch z per XCD -> all 32 z-blocks co-resident, P rows
  // fetched once into that XCD's L2 and read by its 4 d-tiles.
  const int id = blockIdx.x + blockIdx.y * 4 + blockIdx.z * 32;
  const int swz = (id & 7) * 32 + (id >> 3);
  const int z = swz >> 5;
  const int d0 = (swz & 3) * 128;
  const int n0 = ((swz >> 2) & 7) * 256;
  const short* __restrict__ A = Vt + (size_t)z * 1048576;  // [512][2048]
  const short* __restrict__ B = Pm + (size_t)z * 4194304;  // [2048][2048]
  const int t = threadIdx.x;
  const int lane = t & 63, w = t >> 6;
  const int aw = (w >> 2) * 32, bw = (w & 3) * 32;
  const int fr = lane & 15, l4 = lane >> 4;
  const int r0 = t >> 3;
  const int kswz = ((t & 7) ^ (r0 & 7)) * 8;
  const short* pA = A + (size_t)(d0 + r0) * 2048 + kswz;
  const short* pB = B + (size_t)(n0 + r0) * 2048 + kswz;

#define PV_STG_A(buf, h, kt) \
    GLDS(pA + (size_t)((h) * 64) * 2048 + (kt) * 64, &As[(buf)][(h) * 4096 + t * 8])
#define PV_STG_B(buf, h, kt) do { \
    GLDS(pB + (size_t)((h) * 128) * 2048 + (kt) * 64, &Bs[(buf)][(h) * 8192 + t * 8]); \
    GLDS(pB + (size_t)((h) * 128 + 64) * 2048 + (kt) * 64, &Bs[(buf)][(h) * 8192 + 4096 + t * 8]); \
  } while (0)

  f32x4 acc[4][4] = {};

  // prologue: T0 (6 loads) + T1.{A0,B0,B1} (5) = 11; wait ALL of T0 -> vmcnt(5).
  PV_STG_A(0, 0, 0); PV_STG_B(0, 0, 0); PV_STG_B(0, 1, 0); PV_STG_A(0, 1, 0);
  PV_STG_A(1, 0, 1); PV_STG_B(1, 0, 1); PV_STG_B(1, 1, 1);
  VMW(5);
  SBAR();

  bf16x8 a[2][2], b0[2][2], b1[2][2];
  for (int kt = 0; kt < 30; ++kt) {
    const int c = kt & 1;
    const short* Ac = &As[c][0];
    const short* Bc = &Bs[c][0];
    // pha (A0 x {b0,b1})
    ld2(a, Ac, aw + fr, l4); ld2(b0, Bc, bw + fr, l4); ld2(b1, Bc, 128 + bw + fr, l4);
    PV_STG_A(c ^ 1, 1, kt + 1);
    SBAR(); LGKM0_SB(); PRIO1();
    mm22(acc, a, b0, 0, 0); mm22(acc, a, b1, 0, 2);
    PRIO0(); SBAR();
    // phb (A1 x {b1,b0}); stage T(kt+2); single wait for ALL T(kt+1).
    ld2(a, Ac, 64 + aw + fr, l4);
    PV_STG_A(c, 0, kt + 2);
    PV_STG_B(c, 0, kt + 2);
    PV_STG_B(c, 1, kt + 2);
    VMW(5);
    SBAR(); LGKM0_SB(); PRIO1();
    mm22(acc, a, b1, 2, 2); mm22(acc, a, b0, 2, 0);
    PRIO0(); SBAR();
  }
  {  // kt = 30 (buf 0): only T31.A1 left; phb waits ALL T31 -> vmcnt(0).
    const short *Ac = &As[0][0], *Bc = &Bs[0][0];
    ld2(a, Ac, aw + fr, l4); ld2(b0, Bc, bw + fr, l4); ld2(b1, Bc, 128 + bw + fr, l4);
    PV_STG_A(1, 1, 31);
    SBAR(); LGKM0_SB(); PRIO1();
    mm22(acc, a, b0, 0, 0); mm22(acc, a, b1, 0, 2);
    PRIO0(); SBAR();
    ld2(a, Ac, 64 + aw + fr, l4);
    VMW(0);
    SBAR(); LGKM0_SB(); PRIO1();
    mm22(acc, a, b1, 2, 2); mm22(acc, a, b0, 2, 0);
    PRIO0(); SBAR();
  }
  {  // kt = 31 (buf 1): no staging, no vmem waits.
    const short *Ac = &As[1][0], *Bc = &Bs[1][0];
    ld2(a, Ac, aw + fr, l4); ld2(b0, Bc, bw + fr, l4); ld2(b1, Bc, 128 + bw + fr, l4);
    SBAR(); LGKM0_SB(); PRIO1();
    mm22(acc, a, b0, 0, 0); mm22(acc, a, b1, 0, 2);
    PRIO0(); SBAR();
    ld2(a, Ac, 64 + aw + fr, l4);
    LGKM0_SB(); PRIO1();
    mm22(acc, a, b1, 2, 2); mm22(acc, a, b0, 2, 0);
    PRIO0();
  }
#undef PV_STG_A
#undef PV_STG_B

  // epilogue: out = resid + acc * (scale / l[q])
  float linv[4];
#pragma unroll
  for (int n = 0; n < 4; ++n) {
    const int q = n0 + bw + (n & 1) * 16 + (n >> 1) * 128 + fr;
    linv[n] = scale / l[z * 2048 + q];
  }
#pragma unroll
  for (int n = 0; n < 4; ++n) {
    const int q = n0 + bw + (n & 1) * 16 + (n >> 1) * 128 + fr;
#pragma unroll
    for (int i = 0; i < 4; ++i) {
      const int d = d0 + aw + (i & 1) * 16 + (i >> 1) * 64 + l4 * 4;
      const size_t idx = (size_t)z * 1048576 + (size_t)q * 512 + d;
      float4 rv = *(const float4*)(resid + idx);
      float4 o = { rv.x + acc[i][n][0] * linv[n], rv.y + acc[i][n][1] * linv[n],
                   rv.z + acc[i][n][2] * linv[n], rv.w + acc[i][n][3] * linv[n] };
      *(float4*)(out + idx) = o;
    }
  }
}

extern "C" void kernel_launch(void* const* d_in, const int* in_sizes, int n_in,
                              void* d_out, int out_size, void* d_ws, size_t ws_size,
                              hipStream_t stream) {
  const float* feature = (const float*)d_in[0];
  const float* wq = (const float*)d_in[1];
  const float* bq = (const float*)d_in[2];
  const float* wk = (const float*)d_in[3];
  const float* bk = (const float*)d_in[4];
  const float* wv = (const float*)d_in[5];
  const float* bv = (const float*)d_in[6];
  float* out = (float*)d_out;

  const size_t MN = (size_t)16384 * 512;
  short* Xb = (short*)d_ws;       // MN
  short* Wb = Xb + MN;            // 3 * 262144
  short* Q = Wb + 786432;         // MN (K follows contiguously)
  short* K = Q + MN;
  short* Vt = K + MN;             // [8][512][2048]
  short* P = Vt + MN;             // [8][2048][2048] unnormalized exp
  float* biasP = (float*)(P + (size_t)8 * 2048 * 2048);  // [3][512]
  float* l = biasP + 1536;        // [8*2048] row sums of exp

  prep<<<8968, 256, 0, stream>>>(feature, wq, wk, wv, bq, bk, bv, Xb, Wb, biasP, l);

  gemm_qkv<<<dim3(4, 128, 3), 256, 0, stream>>>(Xb, Wb, biasP, Q, Vt);
  gemm_qk8<<<dim3(8, 8, 8), 512, 0, stream>>>(Q, K, P, l);

  const float iscl = 0.044194173824159216f;  // 1/sqrt(512)
  gemm_pv8<<<dim3(4, 8, 8), 512, 0, stream>>>(P, Vt, l, feature, out, iscl);
}